// Round 3
// baseline (1110.286 us; speedup 1.0000x reference)
//
#include <hip/hip_runtime.h>
#include <hip/hip_bf16.h>
#include <hip/hip_cooperative_groups.h>

namespace cg = cooperative_groups;

#define B_ 32
#define T_ 40
#define P_ 256
#define V_ 4096
#define D_ 256
#define DINO_ 384
#define H_ 4
#define L_ 2
#define HD_ 64
#define DFF_ 1024
#define EPS_ 1e-5f

typedef __bf16 bf16;
typedef __bf16 bf16x8 __attribute__((ext_vector_type(8)));
typedef float f32x4 __attribute__((ext_vector_type(4)));

// bf16 weight arena offsets (elements)
#define OFF_QKV 0            // 2 x 768*256
#define OFF_OUTW 393216      // 2 x 256*256
#define OFF_W1 524288        // 2 x 1024*256
#define OFF_W2 1048576       // 2 x 256*1024
#define OFF_FUS 1572864      // 256*640
#define WB_TOTAL 1736704
#define CONV_BLOCKS 848      // WB_TOTAL / 2048
#define PAT_BLOCKS 1536      // 32*256*384 / 2048
#define PREP_UNITS 3728      // 1280 embed + 64 transpose + 848 conv + 1536 pat

__device__ __forceinline__ bf16x8 cvt8(const float* p) {
  float4 f0 = *(const float4*)p;
  float4 f1 = *(const float4*)(p + 4);
  bf16x8 v;
  v[0] = (bf16)f0.x; v[1] = (bf16)f0.y; v[2] = (bf16)f0.z; v[3] = (bf16)f0.w;
  v[4] = (bf16)f1.x; v[5] = (bf16)f1.y; v[6] = (bf16)f1.z; v[7] = (bf16)f1.w;
  return v;
}

// ---- shared-memory shapes --------------------------------------------------
struct GemmSM  { bf16 As[32 * 72];  bf16 Ws[32 * 72]; };   //  9216 B
struct CprojSM { bf16 As[32 * 264]; bf16 Ws[32 * 72]; };   // 21504 B
struct AttnSM  { float q[20][65]; float k[40][65]; float v[40][65]; float s[20][41]; };  // 29280 B
struct PrepSM  { float tile[32][33]; };                    //  4224 B
struct FinalSM { float2 cws[4][D_]; };                     //  8192 B
union __align__(16) MegaSM { GemmSM g; CprojSM c; AttnSM a; PrepSM p; FinalSM f; };

struct Params {
  const float* patches; const int* tokens; const float* tok_emb; const float* pos_emb;
  const float* qkv_w; const float* qkv_b; const float* out_w; const float* out_b;
  const float* ln1_s; const float* ln1_b; const float* w1; const float* b1;
  const float* w2; const float* b2; const float* ln2_s; const float* ln2_b;
  const float* fus_w1; const float* fus_b1; const float* fus_w2; const float* fus_b2;
  const float* cls_w; const float* cls_b; float* out;
  float* x; float* qkvbuf; float* attbuf; float* s; float* pprojT; float* cw;
  bf16* wb; bf16* w2Tb; bf16* patb; bf16* hb;
};

// ---- 32x32 MFMA GEMM tile, round-0 body (KP=64, 2 barriers/chunk) ---------
// ABF16: A is bf16. GATH: A rows gathered via tokens. CW: 0 normal store,
// 1 cw-even(+bias), 2 cw-odd.
template <int ABF16, int OBF16, int RELU, int RESID, int GATH, int CW>
__device__ __forceinline__ void tile_gemm(
    bf16* As, bf16* Ws, const void* Av, const bf16* W, const float* bias,
    const float* resid, const int* tokens, void* outv, int K, int lda,
    int ldw, int ldc, int bm, int bn) {
  const int tid = threadIdx.x;
  const int lane = tid & 63;
  const int wv = tid >> 6;
  const int mi = wv & 1, ni = wv >> 1;
  const int col = lane & 15, quad = lane >> 4;
  const int srow = tid >> 3, kc = (tid & 7) * 8;
  const float* Af = (const float*)Av;
  const bf16* Ab = (const bf16*)Av;
  const float* Ag = GATH ? (Af + (long)tokens[bm + srow] * D_) : nullptr;
  const bf16* Wp = W + (long)(bn + srow) * ldw + kc;

  f32x4 acc = {0.f, 0.f, 0.f, 0.f};
  for (int kk = 0; kk < K; kk += 64) {
    if (GATH)
      *(bf16x8*)&As[srow * 72 + kc] = cvt8(Ag + kk + kc);
    else if (ABF16)
      *(bf16x8*)&As[srow * 72 + kc] = *(const bf16x8*)(Ab + (long)(bm + srow) * lda + kk + kc);
    else
      *(bf16x8*)&As[srow * 72 + kc] = cvt8(Af + (long)(bm + srow) * lda + kk + kc);
    *(bf16x8*)&Ws[srow * 72 + kc] = *(const bf16x8*)(Wp + kk);
    __syncthreads();
#pragma unroll
    for (int ki = 0; ki < 2; ++ki) {
      bf16x8 afr = *(const bf16x8*)&As[(mi * 16 + col) * 72 + ki * 32 + quad * 8];
      bf16x8 bfr = *(const bf16x8*)&Ws[(ni * 16 + col) * 72 + ki * 32 + quad * 8];
      acc = __builtin_amdgcn_mfma_f32_16x16x32_bf16(afr, bfr, acc, 0, 0, 0);
    }
    __syncthreads();
  }
  const int n = bn + ni * 16 + col;
  float bv = bias ? bias[n] : 0.0f;
#pragma unroll
  for (int r = 0; r < 4; ++r) {
    int m = bm + mi * 16 + quad * 4 + r;
    float val = acc[r] + bv;
    if (RESID) val += resid[(long)m * D_ + n];
    if (RELU) val = fmaxf(val, 0.0f);
    if (CW == 1) ((float*)outv)[(long)m * (2 * D_) + n * 2] = val;
    else if (CW == 2) ((float*)outv)[(long)m * (2 * D_) + n * 2 + 1] = val;
    else if (OBF16) ((bf16*)outv)[(long)m * ldc + n] = (bf16)val;
    else ((float*)outv)[(long)m * ldc + n] = val;
  }
}

// ---- stage workers ---------------------------------------------------------
__device__ __forceinline__ void do_prep(PrepSM& ps, const Params& P, int u) {
  int tid = threadIdx.x;
  if (u < 1280) {
    P.x[u * D_ + tid] = P.tok_emb[(long)P.tokens[u] * D_ + tid] + P.pos_emb[(u % T_) * D_ + tid];
  } else if (u < 1344) {
    int tt = u - 1280;
    int bx = (tt & 7) * 32, by = (tt >> 3) * 32;
    int tx = tid & 31, ty = tid >> 5;  // 32 x 8
#pragma unroll
    for (int i = 0; i < 32; i += 8) ps.tile[ty + i][tx] = P.fus_w2[(by + ty + i) * D_ + bx + tx];
    __syncthreads();
#pragma unroll
    for (int i = 0; i < 32; i += 8)
      P.w2Tb[(bx + ty + i) * D_ + by + tx] = (bf16)ps.tile[tx][ty + i];
    __syncthreads();
  } else if (u < 1344 + CONV_BLOCKS) {
    long f = (long)(u - 1344) * 2048 + tid * 8;
    const float* src; long off;
    if (f < OFF_OUTW)      { src = P.qkv_w;  off = f; }
    else if (f < OFF_W1)   { src = P.out_w;  off = f - OFF_OUTW; }
    else if (f < OFF_W2)   { src = P.w1;     off = f - OFF_W1; }
    else if (f < OFF_FUS)  { src = P.w2;     off = f - OFF_W2; }
    else                   { src = P.fus_w1; off = f - OFF_FUS; }
    *(bf16x8*)&P.wb[f] = cvt8(src + off);
  } else {
    long f = (long)(u - 1344 - CONV_BLOCKS) * 2048 + tid * 8;
    *(bf16x8*)&P.patb[f] = cvt8(P.patches + f);
  }
}

__device__ __forceinline__ void do_qkv(GemmSM& g, const Params& P, int l, int u) {
  tile_gemm<0, 0, 0, 0, 0, 0>(g.As, g.Ws, P.x, P.wb + OFF_QKV + (long)l * 3 * D_ * D_,
                              P.qkv_b + l * 3 * D_, nullptr, nullptr, P.qkvbuf,
                              256, D_, D_, 3 * D_, (u / 24) * 32, (u % 24) * 32);
}
__device__ __forceinline__ void do_proj(GemmSM& g, const Params& P, int l, int u) {
  tile_gemm<0, 0, 0, 1, 0, 0>(g.As, g.Ws, P.attbuf, P.wb + OFF_OUTW + (long)l * D_ * D_,
                              P.out_b + l * D_, P.x, nullptr, P.s,
                              256, D_, D_, D_, (u / 8) * 32, (u % 8) * 32);
}
__device__ __forceinline__ void do_w1(GemmSM& g, const Params& P, int l, int u) {
  tile_gemm<0, 1, 1, 0, 0, 0>(g.As, g.Ws, P.x, P.wb + OFF_W1 + (long)l * DFF_ * D_,
                              P.b1 + l * DFF_, nullptr, nullptr, P.hb,
                              256, D_, D_, DFF_, (u / 32) * 32, (u % 32) * 32);
}
__device__ __forceinline__ void do_w2(GemmSM& g, const Params& P, int l, int u) {
  tile_gemm<1, 0, 0, 1, 0, 0>(g.As, g.Ws, P.hb, P.wb + OFF_W2 + (long)l * D_ * DFF_,
                              P.b2 + l * D_, P.x, nullptr, P.s,
                              DFF_, DFF_, DFF_, D_, (u / 8) * 32, (u % 8) * 32);
}
__device__ __forceinline__ void do_pproj(GemmSM& g, const Params& P, int t) {
  int bn = (t & 7) * 32; int y = t >> 3; int bb = y >> 3; int bm = (y & 7) * 32;
  tile_gemm<1, 0, 0, 0, 0, 0>(g.As, g.Ws, P.wb + OFF_FUS, P.patb + (long)bb * P_ * DINO_,
                              nullptr, nullptr, nullptr, P.pprojT + (long)bb * D_ * P_,
                              384, 640, DINO_, P_, bm, bn);
}
__device__ __forceinline__ void do_weff(GemmSM& g, const Params& P, int t) {
  tile_gemm<0, 0, 0, 0, 1, 2>(g.As, g.Ws, P.cls_w, P.w2Tb, nullptr, nullptr,
                              P.tokens, P.cw, 256, D_, D_, D_,
                              (t / 8) * 32, (t % 8) * 32);
}

__device__ __forceinline__ void do_ln(const Params& P, const float* gsc,
                                      const float* be, int u) {
  int wv = threadIdx.x >> 6, lane = threadIdx.x & 63;
  int m = u * 4 + wv;
  float4 v = *(const float4*)(P.s + (long)m * D_ + lane * 4);
  float sum = v.x + v.y + v.z + v.w;
  float ss = v.x * v.x + v.y * v.y + v.z * v.z + v.w * v.w;
#pragma unroll
  for (int mk = 1; mk < 64; mk <<= 1) {
    sum += __shfl_xor(sum, mk);
    ss += __shfl_xor(ss, mk);
  }
  float mean = sum * (1.0f / D_);
  float inv = rsqrtf(ss * (1.0f / D_) - mean * mean + EPS_);
  float4 g4 = *(const float4*)(gsc + lane * 4);
  float4 b4 = *(const float4*)(be + lane * 4);
  float4 o;
  o.x = (v.x - mean) * inv * g4.x + b4.x;
  o.y = (v.y - mean) * inv * g4.y + b4.y;
  o.z = (v.z - mean) * inv * g4.z + b4.z;
  o.w = (v.w - mean) * inv * g4.w + b4.w;
  *(float4*)(P.x + (long)m * D_ + lane * 4) = o;
}

__device__ __forceinline__ void do_attn(AttnSM& A, const Params& P, int u) {
  int h = u & 3, b = (u >> 2) & 31, zq = u >> 7;
  int r0 = zq * 20;
  int tid = threadIdx.x;
  int lane = tid & 63, wv = tid >> 6;
  const float* qkv = P.qkvbuf;
  for (int idx = tid; idx < T_ * HD_; idx += 256) {
    int t = idx >> 6, d = idx & 63;
    long base = (long)(b * T_ + t) * (3 * D_) + h * HD_ + d;
    A.k[t][d] = qkv[base + D_];
    A.v[t][d] = qkv[base + 2 * D_];
    if (t < 20) A.q[t][d] = qkv[(long)(b * T_ + r0 + t) * (3 * D_) + h * HD_ + d];
  }
  __syncthreads();
  for (int idx = tid; idx < 20 * T_; idx += 256) {
    int i = idx / T_, j = idx - i * T_;
    if (j <= r0 + i) {
      float acc = 0.f;
#pragma unroll
      for (int d = 0; d < HD_; ++d) acc += A.q[i][d] * A.k[j][d];
      A.s[i][j] = acc * 0.125f;
    }
  }
  __syncthreads();
  for (int rr = wv; rr < 20; rr += 4) {
    int hi = r0 + rr;
    float val = (lane <= hi) ? A.s[rr][lane] : -1e30f;
    float mx = val;
#pragma unroll
    for (int mk = 1; mk < 64; mk <<= 1) mx = fmaxf(mx, __shfl_xor(mx, mk));
    float e = (lane <= hi)
                  ? __builtin_amdgcn_exp2f((val - mx) * 1.4426950408889634f)
                  : 0.f;
    float sum = e;
#pragma unroll
    for (int mk = 1; mk < 64; mk <<= 1) sum += __shfl_xor(sum, mk);
    float inv = __builtin_amdgcn_rcpf(sum);
    if (lane < T_) A.s[rr][lane] = e * inv;
  }
  __syncthreads();
  for (int idx = tid; idx < 20 * HD_; idx += 256) {
    int i = idx >> 6, d = idx & 63;
    int hi = r0 + i;
    float acc = 0.f;
    for (int j = 0; j <= hi; ++j) acc += A.s[i][j] * A.v[j][d];
    P.attbuf[(long)(b * T_ + hi) * D_ + h * HD_ + d] = acc;
  }
  __syncthreads();
}

__device__ __forceinline__ void do_cproj(CprojSM& c, const Params& P, int bm, int bn) {
  const int tid = threadIdx.x;
  const int lane = tid & 63;
  const int wv = tid >> 6;
  const int mi = wv & 1, ni = wv >> 1;
  const int col = lane & 15, quad = lane >> 4;
  const int srow = tid >> 3, kc = (tid & 7) * 8;
  const int gm = bm + srow;
  f32x4 acc = {0.f, 0.f, 0.f, 0.f};
  const int cg = (tid & 7) * 32;
  const int t = gm % T_;
  if (t == 0) {
    bf16x8 z8 = {};
#pragma unroll
    for (int i = 0; i < 4; ++i) *(bf16x8*)&c.As[srow * 264 + cg + i * 8] = z8;
  } else {
    const float* sp = P.s + (long)(gm - 1) * D_ + cg;
    float v[32];
    float sum = 0.f, ss = 0.f;
#pragma unroll
    for (int i = 0; i < 8; ++i) {
      float4 f = *(const float4*)(sp + i * 4);
      v[i*4] = f.x; v[i*4+1] = f.y; v[i*4+2] = f.z; v[i*4+3] = f.w;
      sum += f.x + f.y + f.z + f.w;
      ss += f.x*f.x + f.y*f.y + f.z*f.z + f.w*f.w;
    }
#pragma unroll
    for (int mk = 1; mk < 8; mk <<= 1) {
      sum += __shfl_xor(sum, mk);
      ss += __shfl_xor(ss, mk);
    }
    float mean = sum * (1.0f / D_);
    float inv = rsqrtf(ss * (1.0f / D_) - mean * mean + EPS_);
    const float* lng = P.ln2_s + D_;
    const float* lnb = P.ln2_b + D_;
#pragma unroll
    for (int i = 0; i < 8; ++i) {
      float4 g4 = *(const float4*)(lng + cg + i * 4);
      float4 b4 = *(const float4*)(lnb + cg + i * 4);
      c.As[srow*264 + cg + i*4]     = (bf16)((v[i*4]   - mean) * inv * g4.x + b4.x);
      c.As[srow*264 + cg + i*4 + 1] = (bf16)((v[i*4+1] - mean) * inv * g4.y + b4.y);
      c.As[srow*264 + cg + i*4 + 2] = (bf16)((v[i*4+2] - mean) * inv * g4.z + b4.z);
      c.As[srow*264 + cg + i*4 + 3] = (bf16)((v[i*4+3] - mean) * inv * g4.w + b4.w);
    }
  }
  __syncthreads();
  const bf16* Wp = P.wb + OFF_FUS + 384 + (long)(bn + srow) * 640 + kc;
  for (int kk = 0; kk < 256; kk += 64) {
    *(bf16x8*)&c.Ws[srow * 72 + kc] = *(const bf16x8*)(Wp + kk);
    __syncthreads();
#pragma unroll
    for (int ki = 0; ki < 2; ++ki) {
      bf16x8 afr = *(const bf16x8*)&c.As[(mi*16 + col) * 264 + kk + ki*32 + quad*8];
      bf16x8 bfr = *(const bf16x8*)&c.Ws[(ni*16 + col) * 72 + ki*32 + quad*8];
      acc = __builtin_amdgcn_mfma_f32_16x16x32_bf16(afr, bfr, acc, 0, 0, 0);
    }
    __syncthreads();
  }
  const int n = bn + ni * 16 + col;
  float bv = P.fus_b1[n];
#pragma unroll
  for (int r = 0; r < 4; ++r) {
    int m = bm + mi * 16 + quad * 4 + r;
    P.cw[(long)m * (2 * D_) + n * 2] = acc[r] + bv;
  }
}

__device__ __forceinline__ void do_final(FinalSM& F, const Params& P, int u) {
  int tid = threadIdx.x;
  int lane = tid & 63, wv = tid >> 6;
  int px = u & 3, rest = u >> 2;
  int ty = rest % 10, b = rest / 10;
  int p = px * 64 + lane;
  int t = ty * 4 + wv;
  int mbase = b * T_ + ty * 4;
  for (int idx = tid; idx < 4 * D_; idx += 256) {
    int tt = idx >> 8, e = idx & 255;
    F.cws[tt][e] = ((const float2*)P.cw)[(long)(mbase + tt) * D_ + e];
  }
  __syncthreads();

  int m = b * T_ + t;
  int tok = P.tokens[m];
  const float* cr = P.cls_w + (long)tok * D_;
  float bacc = 0.f;
#pragma unroll
  for (int i = 0; i < 4; ++i) bacc += cr[lane + i * 64] * P.fus_b2[lane + i * 64];
#pragma unroll
  for (int mk = 1; mk < 64; mk <<= 1) bacc += __shfl_xor(bacc, mk);
  float beff = bacc + P.cls_b[tok];

  const float* ppb = P.pprojT + (long)b * (D_ * P_);  // [e][p]
  float acc = 0.f;
#pragma unroll 8
  for (int e = 0; e < D_; ++e) {
    float pp = ppb[e * P_ + p];
    float2 c = F.cws[wv][e];
    float x = pp + c.x;
    float ex = __builtin_amdgcn_exp2f(-2.4554248f * x);  // -1.702*log2e
    float r = __builtin_amdgcn_rcpf(1.0f + ex);
    acc = fmaf(x * r, c.y, acc);
  }
  float logit = acc + beff;
  float es = __builtin_amdgcn_exp2f(-1.4426950408889634f * logit);
  P.out[(long)(b * P_ + p) * T_ + t] = __builtin_amdgcn_rcpf(1.0f + es);
  __syncthreads();
}

// ---- the persistent cooperative kernel ------------------------------------
__global__ __launch_bounds__(256, 4) void mega_k(Params P) {
  __shared__ MegaSM sm;
  cg::grid_group grid = cg::this_grid();
  const int gs = gridDim.x;
  const int bid = blockIdx.x;

  // S0: prep (embed / transpose / weight-convert / patch-convert)
  for (int u = bid; u < PREP_UNITS; u += gs) do_prep(sm.p, P, u);
  grid.sync();
  // S1: qkv(l=0) 960 + pproj[0..64)
  for (int u = bid; u < 1024; u += gs) {
    if (u < 960) do_qkv(sm.g, P, 0, u);
    else do_pproj(sm.g, P, u - 960);
  }
  grid.sync();
  // S2: attn(l=0) 256 + pproj[64..832)
  for (int u = bid; u < 1024; u += gs) {
    if (u < 256) do_attn(sm.a, P, u);
    else do_pproj(sm.g, P, 64 + u - 256);
  }
  grid.sync();
  // S3: proj(l=0) 320 + pproj[832..1536)
  for (int u = bid; u < 1024; u += gs) {
    if (u < 320) do_proj(sm.g, P, 0, u);
    else do_pproj(sm.g, P, 832 + u - 320);
  }
  grid.sync();
  // S4: ln1(l=0) 320 + pproj[1536..2048) + weff[0..192)
  for (int u = bid; u < 1024; u += gs) {
    if (u < 320) do_ln(P, P.ln1_s, P.ln1_b, u);
    else if (u < 832) do_pproj(sm.g, P, 1536 + u - 320);
    else do_weff(sm.g, P, u - 832);
  }
  grid.sync();
  // S5: w1(l=0) 1280
  for (int u = bid; u < 1280; u += gs) do_w1(sm.g, P, 0, u);
  grid.sync();
  // S6: w2(l=0) 320 + weff[192..320)
  for (int u = bid; u < 448; u += gs) {
    if (u < 320) do_w2(sm.g, P, 0, u);
    else do_weff(sm.g, P, 192 + u - 320);
  }
  grid.sync();
  // S7: ln2(l=0)
  for (int u = bid; u < 320; u += gs) do_ln(P, P.ln2_s, P.ln2_b, u);
  grid.sync();
  // S8: qkv(l=1)
  for (int u = bid; u < 960; u += gs) do_qkv(sm.g, P, 1, u);
  grid.sync();
  // S9: attn(l=1)
  for (int u = bid; u < 256; u += gs) do_attn(sm.a, P, u);
  grid.sync();
  // S10: proj(l=1)
  for (int u = bid; u < 320; u += gs) do_proj(sm.g, P, 1, u);
  grid.sync();
  // S11: ln1(l=1)
  for (int u = bid; u < 320; u += gs) do_ln(P, P.ln1_s + D_, P.ln1_b + D_, u);
  grid.sync();
  // S12: w1(l=1)
  for (int u = bid; u < 1280; u += gs) do_w1(sm.g, P, 1, u);
  grid.sync();
  // S13: w2(l=1)
  for (int u = bid; u < 320; u += gs) do_w2(sm.g, P, 1, u);
  grid.sync();
  // S14: cproj (shifted LN2(l=1) folded)
  for (int u = bid; u < 320; u += gs) do_cproj(sm.c, P, (u / 8) * 32, (u % 8) * 32);
  grid.sync();
  // S15: final
  for (int u = bid; u < 1280; u += gs) do_final(sm.f, P, u);
}

// ---- fallback kernels (round-0 16-launch chain, same device fns) ----------
__global__ __launch_bounds__(256) void fb_prep(Params P) {
  __shared__ PrepSM ps;
  do_prep(ps, P, blockIdx.x);
}
__global__ __launch_bounds__(256) void fb_qkv(Params P, int l) {
  __shared__ GemmSM g; do_qkv(g, P, l, blockIdx.x);
}
__global__ __launch_bounds__(256) void fb_attn(Params P) {
  __shared__ AttnSM a; do_attn(a, P, blockIdx.x);
}
__global__ __launch_bounds__(256) void fb_proj(Params P, int l) {
  __shared__ GemmSM g; do_proj(g, P, l, blockIdx.x);
}
__global__ __launch_bounds__(256) void fb_ln(Params P, const float* gsc, const float* be) {
  do_ln(P, gsc, be, blockIdx.x);
}
__global__ __launch_bounds__(256) void fb_w1(Params P, int l) {
  __shared__ GemmSM g; do_w1(g, P, l, blockIdx.x);
}
__global__ __launch_bounds__(256) void fb_w2(Params P, int l) {
  __shared__ GemmSM g; do_w2(g, P, l, blockIdx.x);
}
__global__ __launch_bounds__(256) void fb_fuse(Params P) {
  __shared__ union { GemmSM g; CprojSM c; } sm;
  int y = blockIdx.y, bx = blockIdx.x;
  if (y < 256) do_pproj(sm.g, P, bx + 8 * y);
  else if (y < 296) do_cproj(sm.c, P, (y - 256) * 32, bx * 32);
  else do_weff(sm.g, P, (y - 296) * 8 + bx);
}
__global__ __launch_bounds__(256) void fb_final(Params P) {
  __shared__ FinalSM f; do_final(f, P, blockIdx.x);
}

extern "C" void kernel_launch(void* const* d_in, const int* in_sizes, int n_in, void* d_out,
                              int out_size, void* d_ws, size_t ws_size, hipStream_t stream) {
  Params P;
  P.patches = (const float*)d_in[0];
  P.tokens = (const int*)d_in[1];
  P.tok_emb = (const float*)d_in[2];
  P.pos_emb = (const float*)d_in[3];
  P.qkv_w = (const float*)d_in[4];
  P.qkv_b = (const float*)d_in[5];
  P.out_w = (const float*)d_in[6];
  P.out_b = (const float*)d_in[7];
  P.ln1_s = (const float*)d_in[8];
  P.ln1_b = (const float*)d_in[9];
  P.w1 = (const float*)d_in[10];
  P.b1 = (const float*)d_in[11];
  P.w2 = (const float*)d_in[12];
  P.b2 = (const float*)d_in[13];
  P.ln2_s = (const float*)d_in[14];
  P.ln2_b = (const float*)d_in[15];
  P.fus_w1 = (const float*)d_in[16];
  P.fus_b1 = (const float*)d_in[17];
  P.fus_w2 = (const float*)d_in[18];
  P.fus_b2 = (const float*)d_in[19];
  P.cls_w = (const float*)d_in[20];
  P.cls_b = (const float*)d_in[21];
  P.out = (float*)d_out;

  const int MT = B_ * T_;  // 1280
  P.x = (float*)d_ws;                          // 1280*256
  P.qkvbuf = P.x + MT * D_;                    // 1280*768
  P.attbuf = P.qkvbuf + MT * 3 * D_;           // 1280*256
  P.s = P.attbuf + MT * D_;                    // 1280*256
  P.pprojT = P.s + MT * D_;                    // 32*256*256 [b][e][p]
  P.cw = P.pprojT + (long)B_ * D_ * P_;        // 1280*512 {cproj,weff}
  P.wb = (bf16*)(P.cw + MT * D_ * 2);          // bf16 weight arena
  P.w2Tb = P.wb + WB_TOTAL;                    // 256*256
  P.patb = P.w2Tb + D_ * D_;                   // 32*256*384
  P.hb = P.patb + (long)B_ * P_ * DINO_;       // 1280*1024 bf16

  // cooperative single-kernel path
  int nb = 0;
  hipError_t qe = hipOccupancyMaxActiveBlocksPerMultiprocessor(&nb, mega_k, 256, 0);
  if (qe == hipSuccess && nb >= 1) {
    int grid = nb * 256;
    if (grid > 1024) grid = 1024;
    void* args[] = {(void*)&P};
    hipError_t le = hipLaunchCooperativeKernel(mega_k, dim3(grid), dim3(256),
                                               args, 0u, stream);
    if (le == hipSuccess) return;
  }

  // fallback: proven multi-launch chain (identical numerics)
  fb_prep<<<PREP_UNITS, 256, 0, stream>>>(P);
  for (int l = 0; l < L_; ++l) {
    fb_qkv<<<960, 256, 0, stream>>>(P, l);
    fb_attn<<<256, 256, 0, stream>>>(P);
    fb_proj<<<320, 256, 0, stream>>>(P, l);
    fb_ln<<<320, 256, 0, stream>>>(P, P.ln1_s + l * D_, P.ln1_b + l * D_);
    fb_w1<<<1280, 256, 0, stream>>>(P, l);
    fb_w2<<<320, 256, 0, stream>>>(P, l);
    if (l == 0) fb_ln<<<320, 256, 0, stream>>>(P, P.ln2_s, P.ln2_b);
  }
  fb_fuse<<<dim3(8, 336), 256, 0, stream>>>(P);
  fb_final<<<1280, 256, 0, stream>>>(P);
}

// Round 4
// 267.290 us; speedup vs baseline: 4.1539x; 4.1539x over previous
//
#include <hip/hip_runtime.h>
#include <hip/hip_bf16.h>

#define B_ 32
#define T_ 40
#define P_ 256
#define V_ 4096
#define D_ 256
#define DINO_ 384
#define H_ 4
#define L_ 2
#define HD_ 64
#define DFF_ 1024
#define EPS_ 1e-5f

typedef __bf16 bf16;
typedef __bf16 bf16x8 __attribute__((ext_vector_type(8)));
typedef float f32x4 __attribute__((ext_vector_type(4)));

// bf16 weight arena offsets (elements)
#define OFF_QKV 0            // 2 x 768*256
#define OFF_OUTW 393216      // 2 x 256*256
#define OFF_W1 524288        // 2 x 1024*256
#define OFF_W2 1048576       // 2 x 256*1024
#define OFF_FUS 1572864      // 256*640
#define WB_TOTAL 1736704
#define CONV_BLOCKS 848      // WB_TOTAL / 2048
#define PAT_BLOCKS 1536      // 32*256*384 / 2048
#define PREP_UNITS 3728      // 1280 embed + 64 transpose + 848 conv + 1536 pat

__device__ __forceinline__ bf16x8 cvt8(const float* p) {
  float4 f0 = *(const float4*)p;
  float4 f1 = *(const float4*)(p + 4);
  bf16x8 v;
  v[0] = (bf16)f0.x; v[1] = (bf16)f0.y; v[2] = (bf16)f0.z; v[3] = (bf16)f0.w;
  v[4] = (bf16)f1.x; v[5] = (bf16)f1.y; v[6] = (bf16)f1.z; v[7] = (bf16)f1.w;
  return v;
}

// ---- shared-memory shapes --------------------------------------------------
struct GemmSM  { bf16 As[32 * 72];  bf16 Ws[32 * 72]; };   //  9216 B
struct CprojSM { bf16 As[32 * 264]; bf16 Ws[32 * 72]; };   // 21504 B
struct AttnSM  { float q[20][65]; float k[40][65]; float v[40][65]; float s[20][41]; };  // 29280 B
struct PrepSM  { float tile[32][33]; };                    //  4224 B
struct FinalSM { float2 cws[4][D_]; };                     //  8192 B
struct RowSM   { bf16 As[32 * 72];  bf16 Ws[256 * 72]; };  // 41472 B

struct Params {
  const float* patches; const int* tokens; const float* tok_emb; const float* pos_emb;
  const float* qkv_w; const float* qkv_b; const float* out_w; const float* out_b;
  const float* ln1_s; const float* ln1_b; const float* w1; const float* b1;
  const float* w2; const float* b2; const float* ln2_s; const float* ln2_b;
  const float* fus_w1; const float* fus_b1; const float* fus_w2; const float* fus_b2;
  const float* cls_w; const float* cls_b; float* out;
  float* x; float* qkvbuf; float* attbuf; float* s; float* pprojT; float* cw;
  bf16* wb; bf16* w2Tb; bf16* patb; bf16* hb;
};

// ---- 32x32 MFMA GEMM tile (round-0 verified body) -------------------------
template <int ABF16, int OBF16, int RELU, int RESID, int GATH, int CW>
__device__ __forceinline__ void tile_gemm(
    bf16* As, bf16* Ws, const void* Av, const bf16* W, const float* bias,
    const float* resid, const int* tokens, void* outv, int K, int lda,
    int ldw, int ldc, int bm, int bn) {
  const int tid = threadIdx.x;
  const int lane = tid & 63;
  const int wv = tid >> 6;
  const int mi = wv & 1, ni = wv >> 1;
  const int col = lane & 15, quad = lane >> 4;
  const int srow = tid >> 3, kc = (tid & 7) * 8;
  const float* Af = (const float*)Av;
  const bf16* Ab = (const bf16*)Av;
  const float* Ag = GATH ? (Af + (long)tokens[bm + srow] * D_) : nullptr;
  const bf16* Wp = W + (long)(bn + srow) * ldw + kc;

  f32x4 acc = {0.f, 0.f, 0.f, 0.f};
  for (int kk = 0; kk < K; kk += 64) {
    if (GATH)
      *(bf16x8*)&As[srow * 72 + kc] = cvt8(Ag + kk + kc);
    else if (ABF16)
      *(bf16x8*)&As[srow * 72 + kc] = *(const bf16x8*)(Ab + (long)(bm + srow) * lda + kk + kc);
    else
      *(bf16x8*)&As[srow * 72 + kc] = cvt8(Af + (long)(bm + srow) * lda + kk + kc);
    *(bf16x8*)&Ws[srow * 72 + kc] = *(const bf16x8*)(Wp + kk);
    __syncthreads();
#pragma unroll
    for (int ki = 0; ki < 2; ++ki) {
      bf16x8 afr = *(const bf16x8*)&As[(mi * 16 + col) * 72 + ki * 32 + quad * 8];
      bf16x8 bfr = *(const bf16x8*)&Ws[(ni * 16 + col) * 72 + ki * 32 + quad * 8];
      acc = __builtin_amdgcn_mfma_f32_16x16x32_bf16(afr, bfr, acc, 0, 0, 0);
    }
    __syncthreads();
  }
  const int n = bn + ni * 16 + col;
  float bv = bias ? bias[n] : 0.0f;
#pragma unroll
  for (int r = 0; r < 4; ++r) {
    int m = bm + mi * 16 + quad * 4 + r;
    float val = acc[r] + bv;
    if (RESID) val += resid[(long)m * D_ + n];
    if (RELU) val = fmaxf(val, 0.0f);
    if (CW == 1) ((float*)outv)[(long)m * (2 * D_) + n * 2] = val;
    else if (CW == 2) ((float*)outv)[(long)m * (2 * D_) + n * 2 + 1] = val;
    else if (OBF16) ((bf16*)outv)[(long)m * ldc + n] = (bf16)val;
    else ((float*)outv)[(long)m * ldc + n] = val;
  }
}

// ---- stage workers (verified in round-3 mega run) -------------------------
__device__ __forceinline__ void do_prep(PrepSM& ps, const Params& P, int u) {
  int tid = threadIdx.x;
  if (u < 1280) {
    P.x[u * D_ + tid] = P.tok_emb[(long)P.tokens[u] * D_ + tid] + P.pos_emb[(u % T_) * D_ + tid];
  } else if (u < 1344) {
    int tt = u - 1280;
    int bx = (tt & 7) * 32, by = (tt >> 3) * 32;
    int tx = tid & 31, ty = tid >> 5;  // 32 x 8
#pragma unroll
    for (int i = 0; i < 32; i += 8) ps.tile[ty + i][tx] = P.fus_w2[(by + ty + i) * D_ + bx + tx];
    __syncthreads();
#pragma unroll
    for (int i = 0; i < 32; i += 8)
      P.w2Tb[(bx + ty + i) * D_ + by + tx] = (bf16)ps.tile[tx][ty + i];
  } else if (u < 1344 + CONV_BLOCKS) {
    long f = (long)(u - 1344) * 2048 + tid * 8;
    const float* src; long off;
    if (f < OFF_OUTW)      { src = P.qkv_w;  off = f; }
    else if (f < OFF_W1)   { src = P.out_w;  off = f - OFF_OUTW; }
    else if (f < OFF_W2)   { src = P.w1;     off = f - OFF_W1; }
    else if (f < OFF_FUS)  { src = P.w2;     off = f - OFF_W2; }
    else                   { src = P.fus_w1; off = f - OFF_FUS; }
    *(bf16x8*)&P.wb[f] = cvt8(src + off);
  } else {
    long f = (long)(u - 1344 - CONV_BLOCKS) * 2048 + tid * 8;
    *(bf16x8*)&P.patb[f] = cvt8(P.patches + f);
  }
}

__device__ __forceinline__ void do_qkv(GemmSM& g, const Params& P, int l, int u) {
  tile_gemm<0, 0, 0, 0, 0, 0>(g.As, g.Ws, P.x, P.wb + OFF_QKV + (long)l * 3 * D_ * D_,
                              P.qkv_b + l * 3 * D_, nullptr, nullptr, P.qkvbuf,
                              256, D_, D_, 3 * D_, (u / 24) * 32, (u % 24) * 32);
}
__device__ __forceinline__ void do_w1(GemmSM& g, const Params& P, int l, int u) {
  tile_gemm<0, 1, 1, 0, 0, 0>(g.As, g.Ws, P.x, P.wb + OFF_W1 + (long)l * DFF_ * D_,
                              P.b1 + l * DFF_, nullptr, nullptr, P.hb,
                              256, D_, D_, DFF_, (u / 32) * 32, (u % 32) * 32);
}
__device__ __forceinline__ void do_w2(GemmSM& g, const Params& P, int l, int u) {
  tile_gemm<1, 0, 0, 1, 0, 0>(g.As, g.Ws, P.hb, P.wb + OFF_W2 + (long)l * D_ * DFF_,
                              P.b2 + l * D_, P.x, nullptr, P.s,
                              DFF_, DFF_, DFF_, D_, (u / 8) * 32, (u % 8) * 32);
}
__device__ __forceinline__ void do_pproj(GemmSM& g, const Params& P, int t) {
  int bn = (t & 7) * 32; int y = t >> 3; int bb = y >> 3; int bm = (y & 7) * 32;
  tile_gemm<1, 0, 0, 0, 0, 0>(g.As, g.Ws, P.wb + OFF_FUS, P.patb + (long)bb * P_ * DINO_,
                              nullptr, nullptr, nullptr, P.pprojT + (long)bb * D_ * P_,
                              384, 640, DINO_, P_, bm, bn);
}
__device__ __forceinline__ void do_weff(GemmSM& g, const Params& P, int t) {
  tile_gemm<0, 0, 0, 0, 1, 2>(g.As, g.Ws, P.cls_w, P.w2Tb, nullptr, nullptr,
                              P.tokens, P.cw, 256, D_, D_, D_,
                              (t / 8) * 32, (t % 8) * 32);
}

__device__ __forceinline__ void do_attn(AttnSM& A, const Params& P, int u) {
  int h = u & 3, b = (u >> 2) & 31, zq = u >> 7;
  int r0 = zq * 20;
  int tid = threadIdx.x;
  int lane = tid & 63, wv = tid >> 6;
  const float* qkv = P.qkvbuf;
  for (int idx = tid; idx < T_ * HD_; idx += 256) {
    int t = idx >> 6, d = idx & 63;
    long base = (long)(b * T_ + t) * (3 * D_) + h * HD_ + d;
    A.k[t][d] = qkv[base + D_];
    A.v[t][d] = qkv[base + 2 * D_];
    if (t < 20) A.q[t][d] = qkv[(long)(b * T_ + r0 + t) * (3 * D_) + h * HD_ + d];
  }
  __syncthreads();
  for (int idx = tid; idx < 20 * T_; idx += 256) {
    int i = idx / T_, j = idx - i * T_;
    if (j <= r0 + i) {
      float acc = 0.f;
#pragma unroll
      for (int d = 0; d < HD_; ++d) acc += A.q[i][d] * A.k[j][d];
      A.s[i][j] = acc * 0.125f;
    }
  }
  __syncthreads();
  for (int rr = wv; rr < 20; rr += 4) {
    int hi = r0 + rr;
    float val = (lane <= hi) ? A.s[rr][lane] : -1e30f;
    float mx = val;
#pragma unroll
    for (int mk = 1; mk < 64; mk <<= 1) mx = fmaxf(mx, __shfl_xor(mx, mk));
    float e = (lane <= hi)
                  ? __builtin_amdgcn_exp2f((val - mx) * 1.4426950408889634f)
                  : 0.f;
    float sum = e;
#pragma unroll
    for (int mk = 1; mk < 64; mk <<= 1) sum += __shfl_xor(sum, mk);
    float inv = __builtin_amdgcn_rcpf(sum);
    if (lane < T_) A.s[rr][lane] = e * inv;
  }
  __syncthreads();
  for (int idx = tid; idx < 20 * HD_; idx += 256) {
    int i = idx >> 6, d = idx & 63;
    int hi = r0 + i;
    float acc = 0.f;
    for (int j = 0; j <= hi; ++j) acc += A.s[i][j] * A.v[j][d];
    P.attbuf[(long)(b * T_ + hi) * D_ + h * HD_ + d] = acc;
  }
}

__device__ __forceinline__ void do_cproj(CprojSM& c, const Params& P, int bm, int bn) {
  const int tid = threadIdx.x;
  const int lane = tid & 63;
  const int wv = tid >> 6;
  const int mi = wv & 1, ni = wv >> 1;
  const int col = lane & 15, quad = lane >> 4;
  const int srow = tid >> 3, kc = (tid & 7) * 8;
  const int gm = bm + srow;
  f32x4 acc = {0.f, 0.f, 0.f, 0.f};
  const int cg = (tid & 7) * 32;
  const int t = gm % T_;
  if (t == 0) {
    bf16x8 z8 = {};
#pragma unroll
    for (int i = 0; i < 4; ++i) *(bf16x8*)&c.As[srow * 264 + cg + i * 8] = z8;
  } else {
    const float* sp = P.s + (long)(gm - 1) * D_ + cg;
    float v[32];
    float sum = 0.f, ss = 0.f;
#pragma unroll
    for (int i = 0; i < 8; ++i) {
      float4 f = *(const float4*)(sp + i * 4);
      v[i*4] = f.x; v[i*4+1] = f.y; v[i*4+2] = f.z; v[i*4+3] = f.w;
      sum += f.x + f.y + f.z + f.w;
      ss += f.x*f.x + f.y*f.y + f.z*f.z + f.w*f.w;
    }
#pragma unroll
    for (int mk = 1; mk < 8; mk <<= 1) {
      sum += __shfl_xor(sum, mk);
      ss += __shfl_xor(ss, mk);
    }
    float mean = sum * (1.0f / D_);
    float inv = rsqrtf(ss * (1.0f / D_) - mean * mean + EPS_);
    const float* lng = P.ln2_s + D_;
    const float* lnb = P.ln2_b + D_;
#pragma unroll
    for (int i = 0; i < 8; ++i) {
      float4 g4 = *(const float4*)(lng + cg + i * 4);
      float4 b4 = *(const float4*)(lnb + cg + i * 4);
      c.As[srow*264 + cg + i*4]     = (bf16)((v[i*4]   - mean) * inv * g4.x + b4.x);
      c.As[srow*264 + cg + i*4 + 1] = (bf16)((v[i*4+1] - mean) * inv * g4.y + b4.y);
      c.As[srow*264 + cg + i*4 + 2] = (bf16)((v[i*4+2] - mean) * inv * g4.z + b4.z);
      c.As[srow*264 + cg + i*4 + 3] = (bf16)((v[i*4+3] - mean) * inv * g4.w + b4.w);
    }
  }
  __syncthreads();
  const bf16* Wp = P.wb + OFF_FUS + 384 + (long)(bn + srow) * 640 + kc;
  for (int kk = 0; kk < 256; kk += 64) {
    *(bf16x8*)&c.Ws[srow * 72 + kc] = *(const bf16x8*)(Wp + kk);
    __syncthreads();
#pragma unroll
    for (int ki = 0; ki < 2; ++ki) {
      bf16x8 afr = *(const bf16x8*)&c.As[(mi*16 + col) * 264 + kk + ki*32 + quad*8];
      bf16x8 bfr = *(const bf16x8*)&c.Ws[(ni*16 + col) * 72 + ki*32 + quad*8];
      acc = __builtin_amdgcn_mfma_f32_16x16x32_bf16(afr, bfr, acc, 0, 0, 0);
    }
    __syncthreads();
  }
  const int n = bn + ni * 16 + col;
  float bv = P.fus_b1[n];
#pragma unroll
  for (int r = 0; r < 4; ++r) {
    int m = bm + mi * 16 + quad * 4 + r;
    P.cw[(long)m * (2 * D_) + n * 2] = acc[r] + bv;
  }
}

__device__ __forceinline__ void do_final(FinalSM& F, const Params& P, int u) {
  int tid = threadIdx.x;
  int lane = tid & 63, wv = tid >> 6;
  int px = u & 3, rest = u >> 2;
  int ty = rest % 10, b = rest / 10;
  int p = px * 64 + lane;
  int t = ty * 4 + wv;
  int mbase = b * T_ + ty * 4;
  for (int idx = tid; idx < 4 * D_; idx += 256) {
    int tt = idx >> 8, e = idx & 255;
    F.cws[tt][e] = ((const float2*)P.cw)[(long)(mbase + tt) * D_ + e];
  }
  __syncthreads();

  int m = b * T_ + t;
  int tok = P.tokens[m];
  const float* cr = P.cls_w + (long)tok * D_;
  float bacc = 0.f;
#pragma unroll
  for (int i = 0; i < 4; ++i) bacc += cr[lane + i * 64] * P.fus_b2[lane + i * 64];
#pragma unroll
  for (int mk = 1; mk < 64; mk <<= 1) bacc += __shfl_xor(bacc, mk);
  float beff = bacc + P.cls_b[tok];

  const float* ppb = P.pprojT + (long)b * (D_ * P_);  // [e][p]
  float acc = 0.f;
#pragma unroll 8
  for (int e = 0; e < D_; ++e) {
    float pp = ppb[e * P_ + p];
    float2 c = F.cws[wv][e];
    float x = pp + c.x;
    float ex = __builtin_amdgcn_exp2f(-2.4554248f * x);  // -1.702*log2e
    float r = __builtin_amdgcn_rcpf(1.0f + ex);
    acc = fmaf(x * r, c.y, acc);
  }
  float logit = acc + beff;
  float es = __builtin_amdgcn_exp2f(-1.4426950408889634f * logit);
  P.out[(long)(b * P_ + p) * T_ + t] = __builtin_amdgcn_rcpf(1.0f + es);
}

// ---- NEW: row-strip GEMM (32 rows x all 256 cols) + in-epilogue LayerNorm -
// One block owns full output rows -> LN computed exactly once, no extra
// launch, no cross-block redundancy. resid/xout may alias (row-disjoint
// blocks; reads complete before the post-barrier writes).
template <int ABF16>
__global__ __launch_bounds__(256) void rowln_k(
    const void* __restrict__ Av, const bf16* __restrict__ W,
    const float* __restrict__ bias, const float* __restrict__ resid,
    const float* __restrict__ lng, const float* __restrict__ lnb,
    float* __restrict__ xout, int K, int lda, int ldw) {
  __shared__ RowSM sm;
  const int tid = threadIdx.x;
  const int lane = tid & 63;
  const int wv = tid >> 6;
  const int mi = wv & 1, nh = wv >> 1;
  const int col = lane & 15, quad = lane >> 4;
  const int srow = tid >> 3, kc = (tid & 7) * 8;
  const int bm = blockIdx.x * 32;
  const float* Af = (const float*)Av;
  const bf16* Ab = (const bf16*)Av;

  f32x4 acc[8];
#pragma unroll
  for (int i = 0; i < 8; ++i) acc[i] = (f32x4){0.f, 0.f, 0.f, 0.f};

  for (int kk = 0; kk < K; kk += 64) {
    if (ABF16)
      *(bf16x8*)&sm.As[srow * 72 + kc] =
          *(const bf16x8*)(Ab + (long)(bm + srow) * lda + kk + kc);
    else
      *(bf16x8*)&sm.As[srow * 72 + kc] = cvt8(Af + (long)(bm + srow) * lda + kk + kc);
    {
      const bf16* wp = W + (long)tid * ldw + kk;  // thread stages W row n=tid
#pragma unroll
      for (int j = 0; j < 8; ++j)
        *(bf16x8*)&sm.Ws[tid * 72 + j * 8] = *(const bf16x8*)(wp + j * 8);
    }
    __syncthreads();
#pragma unroll
    for (int nn = 0; nn < 8; ++nn) {
      const int ni = nh * 8 + nn;
#pragma unroll
      for (int ki = 0; ki < 2; ++ki) {
        bf16x8 afr = *(const bf16x8*)&sm.As[(mi * 16 + col) * 72 + ki * 32 + quad * 8];
        bf16x8 bfr = *(const bf16x8*)&sm.Ws[(ni * 16 + col) * 72 + ki * 32 + quad * 8];
        acc[nn] = __builtin_amdgcn_mfma_f32_16x16x32_bf16(afr, bfr, acc[nn], 0, 0, 0);
      }
    }
    __syncthreads();
  }

  // epilogue: bias + residual -> LDS fp32 strip
  float* S = (float*)sm.Ws;  // 32 x 260 fp32 = 33280 B (fits in Ws)
#pragma unroll
  for (int nn = 0; nn < 8; ++nn) {
    const int n = (nh * 8 + nn) * 16 + col;
    const float bv = bias[n];
#pragma unroll
    for (int r = 0; r < 4; ++r) {
      const int m = mi * 16 + quad * 4 + r;
      S[m * 260 + n] = acc[nn][r] + bv + resid[(long)(bm + m) * D_ + n];
    }
  }
  __syncthreads();
  {
    const int row = tid >> 3, cg = (tid & 7) * 32;
    float v[32];
    float sum = 0.f, ss = 0.f;
#pragma unroll
    for (int i = 0; i < 8; ++i) {
      float4 f = *(const float4*)&S[row * 260 + cg + i * 4];
      v[i*4] = f.x; v[i*4+1] = f.y; v[i*4+2] = f.z; v[i*4+3] = f.w;
      sum += f.x + f.y + f.z + f.w;
      ss += f.x*f.x + f.y*f.y + f.z*f.z + f.w*f.w;
    }
#pragma unroll
    for (int mk = 1; mk < 8; mk <<= 1) {
      sum += __shfl_xor(sum, mk);
      ss += __shfl_xor(ss, mk);
    }
    const float mean = sum * (1.0f / D_);
    const float inv = rsqrtf(ss * (1.0f / D_) - mean * mean + EPS_);
#pragma unroll
    for (int i = 0; i < 8; ++i) {
      float4 g4 = *(const float4*)(lng + cg + i * 4);
      float4 b4 = *(const float4*)(lnb + cg + i * 4);
      float4 o;
      o.x = (v[i*4]   - mean) * inv * g4.x + b4.x;
      o.y = (v[i*4+1] - mean) * inv * g4.y + b4.y;
      o.z = (v[i*4+2] - mean) * inv * g4.z + b4.z;
      o.w = (v[i*4+3] - mean) * inv * g4.w + b4.w;
      *(float4*)(xout + (long)(bm + row) * D_ + cg + i * 4) = o;
    }
  }
}

// ---- launch wrappers -------------------------------------------------------
__global__ __launch_bounds__(256) void prep_k(Params P) {
  __shared__ PrepSM ps; do_prep(ps, P, blockIdx.x);
}
__global__ __launch_bounds__(256) void qkv_k(Params P, int l) {
  __shared__ GemmSM g; do_qkv(g, P, l, blockIdx.x);
}
// attn + pproj + weff co-launch (pproj/weff independent of encoder state)
__global__ __launch_bounds__(256) void apw_k(Params P) {
  __shared__ union __align__(16) { AttnSM a; GemmSM g; } sm;
  int bid = blockIdx.x;
  if (bid < 256) do_attn(sm.a, P, bid);
  else if (bid < 2304) do_pproj(sm.g, P, bid - 256);
  else do_weff(sm.g, P, bid - 2304);
}
__global__ __launch_bounds__(256) void attn_k(Params P) {
  __shared__ AttnSM a; do_attn(a, P, blockIdx.x);
}
__global__ __launch_bounds__(256) void w1_k(Params P, int l) {
  __shared__ GemmSM g; do_w1(g, P, l, blockIdx.x);
}
__global__ __launch_bounds__(256) void w2_k(Params P, int l) {
  __shared__ GemmSM g; do_w2(g, P, l, blockIdx.x);
}
__global__ __launch_bounds__(256) void cproj_k(Params P) {
  __shared__ CprojSM c; do_cproj(c, P, blockIdx.y * 32, blockIdx.x * 32);
}
__global__ __launch_bounds__(256) void final_k(Params P) {
  __shared__ FinalSM f; do_final(f, P, blockIdx.x);
}

extern "C" void kernel_launch(void* const* d_in, const int* in_sizes, int n_in, void* d_out,
                              int out_size, void* d_ws, size_t ws_size, hipStream_t stream) {
  Params P;
  P.patches = (const float*)d_in[0];
  P.tokens = (const int*)d_in[1];
  P.tok_emb = (const float*)d_in[2];
  P.pos_emb = (const float*)d_in[3];
  P.qkv_w = (const float*)d_in[4];
  P.qkv_b = (const float*)d_in[5];
  P.out_w = (const float*)d_in[6];
  P.out_b = (const float*)d_in[7];
  P.ln1_s = (const float*)d_in[8];
  P.ln1_b = (const float*)d_in[9];
  P.w1 = (const float*)d_in[10];
  P.b1 = (const float*)d_in[11];
  P.w2 = (const float*)d_in[12];
  P.b2 = (const float*)d_in[13];
  P.ln2_s = (const float*)d_in[14];
  P.ln2_b = (const float*)d_in[15];
  P.fus_w1 = (const float*)d_in[16];
  P.fus_b1 = (const float*)d_in[17];
  P.fus_w2 = (const float*)d_in[18];
  P.fus_b2 = (const float*)d_in[19];
  P.cls_w = (const float*)d_in[20];
  P.cls_b = (const float*)d_in[21];
  P.out = (float*)d_out;

  const int MT = B_ * T_;  // 1280
  P.x = (float*)d_ws;                          // 1280*256
  P.qkvbuf = P.x + MT * D_;                    // 1280*768
  P.attbuf = P.qkvbuf + MT * 3 * D_;           // 1280*256
  P.s = P.attbuf + MT * D_;                    // 1280*256
  P.pprojT = P.s + MT * D_;                    // 32*256*256 [b][e][p]
  P.cw = P.pprojT + (long)B_ * D_ * P_;        // 1280*512 {cproj,weff}
  P.wb = (bf16*)(P.cw + MT * D_ * 2);          // bf16 weight arena
  P.w2Tb = P.wb + WB_TOTAL;                    // 256*256
  P.patb = P.w2Tb + D_ * D_;                   // 32*256*384
  P.hb = P.patb + (long)B_ * P_ * DINO_;       // 1280*1024 bf16

  // 1. prep: embed->x, fus_w2 transpose, weights->bf16, patches->bf16
  prep_k<<<PREP_UNITS, 256, 0, stream>>>(P);
  // 2. qkv(l=0)
  qkv_k<<<960, 256, 0, stream>>>(P, 0);
  // 3. attn(l=0) + pproj + weff (both encoder-independent, fill idle CUs)
  apw_k<<<2624, 256, 0, stream>>>(P);
  // 4. proj(l=0)+resid+LN1 fused row-strip -> x
  rowln_k<0><<<40, 256, 0, stream>>>(P.attbuf, P.wb + OFF_OUTW, P.out_b, P.x,
                                     P.ln1_s, P.ln1_b, P.x, 256, 256, 256);
  // 5. w1(l=0): hb = relu(x @ w1^T + b1)
  w1_k<<<1280, 256, 0, stream>>>(P, 0);
  // 6. w2(l=0)+resid+LN2 fused row-strip -> x
  rowln_k<1><<<40, 256, 0, stream>>>(P.hb, P.wb + OFF_W2, P.b2, P.x,
                                     P.ln2_s, P.ln2_b, P.x, 1024, 1024, 1024);
  // 7. qkv(l=1)
  qkv_k<<<960, 256, 0, stream>>>(P, 1);
  // 8. attn(l=1)
  attn_k<<<256, 256, 0, stream>>>(P);
  // 9. proj(l=1)+resid+LN1 fused row-strip -> x
  rowln_k<0><<<40, 256, 0, stream>>>(P.attbuf, P.wb + OFF_OUTW + D_ * D_,
                                     P.out_b + D_, P.x, P.ln1_s + D_,
                                     P.ln1_b + D_, P.x, 256, 256, 256);
  // 10. w1(l=1)
  w1_k<<<1280, 256, 0, stream>>>(P, 1);
  // 11. w2(l=1): s = hb @ w2^T + b2 + x  (pre-LN sum needed by cproj shift)
  w2_k<<<320, 256, 0, stream>>>(P, 1);
  // 12. cproj: shifted LN2(l=1) folded -> cw even (+fus_b1)
  cproj_k<<<dim3(8, 40), 256, 0, stream>>>(P);
  // 13. final
  final_k<<<1280, 256, 0, stream>>>(P);
}